// Round 3
// baseline (201.739 us; speedup 1.0000x reference)
//
#include <hip/hip_runtime.h>

// Problem constants (match reference)
#define B_ 64
#define T_ 4096
#define C_ 8
#define K_ 150

constexpr int TPB     = 256;  // threads per block
constexpr int TCHUNK  = 256;  // timesteps per block (1 per thread)
constexpr int NACC    = 27;   // 24 num (3k x 8c) + 3 den per lane
constexpr int RSTRIDE = 29;   // odd stride -> <=2-way LDS bank aliasing (free)

#if __has_builtin(__builtin_amdgcn_exp2f)
#define EXP2F(x) __builtin_amdgcn_exp2f(x)
#else
#define EXP2F(x) __expf((x) * 0.6931471805599453f)
#endif

// Zero the numerator region (in d_out) and denominator region (in d_ws).
__global__ void zero_accum(float* __restrict__ patch, float* __restrict__ den_g) {
    int i = blockIdx.x * blockDim.x + threadIdx.x;
    int n_patch = B_ * K_ * C_;           // 76800
    int n_total = n_patch + B_ * K_;      // +9600
    if (i < n_patch)      patch[i] = 0.0f;
    else if (i < n_total) den_g[i - n_patch] = 0.0f;
}

__global__ __launch_bounds__(TPB) void softkmeans_main(
        const float* __restrict__ x,        // [B,T,C]
        const float* __restrict__ cent,     // [K,C]
        float* __restrict__ assign_out,     // [B,T,K]
        float* __restrict__ num_g,          // [B,K,C] accumulator (in d_out)
        float* __restrict__ den_g) {        // [B,K]   accumulator (in d_ws)
    __shared__ float4 xt[TCHUNK * 2];      // 8.0 KB: x tile [t][c] as 2x float4
    __shared__ float4 cent2[K_ * 2];       // 4.8 KB: centroids scaled by 2*log2e
    __shared__ float  cs[K_];              // 0.6 KB: log2e * |c_k|^2
    __shared__ float  red[64 * RSTRIDE];   // 7.4 KB: cross-wave reduction
    // total ~21 KB -> LDS allows >4 blocks/CU (VGPRs become the cap)

    const int bx    = blockIdx.x;
    const int b     = bx >> 4;             // 16 chunks per batch
    const int chunk = bx & 15;
    const int t0    = chunk * TCHUNK;
    const int tid   = threadIdx.x;
    const int wave  = tid >> 6;
    const int lane  = tid & 63;

    const float LOG2E = 1.4426950408889634f;

    // ---- staging (single barrier) ----
    const float4* xsrc = (const float4*)(x + ((size_t)b * T_ + t0) * C_);
    xt[tid]       = xsrc[tid];
    xt[tid + TPB] = xsrc[tid + TPB];

    // per-lane x for pass 1 (thread tid owns t_local = tid): coalesced dwordx4 pairs
    float4 xa = xsrc[2 * tid];
    float4 xb = xsrc[2 * tid + 1];

    // centroids scaled into exp2 domain: cent2 = 2*log2e*c  (300 float4s)
    {
        const float4* cf4 = (const float4*)cent;
        const float s2 = 2.0f * LOG2E;
        float4 v = cf4[tid];
        v.x *= s2; v.y *= s2; v.z *= s2; v.w *= s2;
        cent2[tid] = v;
        if (tid < 2 * K_ - TPB) {
            float4 w = cf4[tid + TPB];
            w.x *= s2; w.y *= s2; w.z *= s2; w.w *= s2;
            cent2[tid + TPB] = w;
        }
    }
    // cs[k] = log2e * |c_k|^2 (from global; tiny, L2-resident)
    if (tid < K_) {
        float s = 0.0f;
#pragma unroll
        for (int c = 0; c < C_; ++c) {
            float v = cent[tid * C_ + c];
            s += v * v;
        }
        cs[tid] = LOG2E * s;
    }
    __syncthreads();

    // ---- pass 1: t-ownership, per-lane softmax denominator (no cross-lane ops)
    // e_{t,k} = exp2( dot(cent2_k, x_t) - cs_k );  |x|^2 cancels in softmax.
    float s1 = 0.0f;
#pragma unroll 2
    for (int k = 0; k < K_; ++k) {
        float4 c0 = cent2[2 * k];       // broadcast LDS reads: conflict-free
        float4 c1 = cent2[2 * k + 1];
        float acc = -cs[k];
        acc = fmaf(c0.x, xa.x, acc); acc = fmaf(c0.y, xa.y, acc);
        acc = fmaf(c0.z, xa.z, acc); acc = fmaf(c0.w, xa.w, acc);
        acc = fmaf(c1.x, xb.x, acc); acc = fmaf(c1.y, xb.y, acc);
        acc = fmaf(c1.z, xb.z, acc); acc = fmaf(c1.w, xb.w, acc);
        s1 += EXP2F(acc);
    }
    float inv_own = __builtin_amdgcn_rcpf(s1);  // rel err ~1e-7 vs 2.4e-3 tol

    // ---- pass 2: k-ownership; inv comes from pass-1 regs via readlane
    // (wave w's lanes own exactly the 64 t's wave w iterates: no barrier needed)
    float cen[3][C_];
    float csq2[3];
#pragma unroll
    for (int j = 0; j < 3; ++j) {
        int k = lane + 64 * j;
        if (k < K_) {
            float4 c0 = cent2[2 * k];
            float4 c1 = cent2[2 * k + 1];
            cen[j][0] = c0.x; cen[j][1] = c0.y; cen[j][2] = c0.z; cen[j][3] = c0.w;
            cen[j][4] = c1.x; cen[j][5] = c1.y; cen[j][6] = c1.z; cen[j][7] = c1.w;
            csq2[j] = cs[k];
        } else {
#pragma unroll
            for (int c = 0; c < C_; ++c) cen[j][c] = 0.0f;
            csq2[j] = 1e30f;   // exp2(-1e30) = 0: dead lane contributes nothing
        }
    }

    float num[3][C_] = {};
    float den[3] = {0.0f, 0.0f, 0.0f};

    float* aout = assign_out + ((size_t)(b * T_ + t0 + wave * 64)) * K_;
#pragma unroll 2
    for (int tt = 0; tt < 64; ++tt) {
        const int tl = wave * 64 + tt;
        float4 x0 = xt[tl * 2];            // broadcast: conflict-free
        float4 x1 = xt[tl * 2 + 1];
        float xv[C_] = {x0.x, x0.y, x0.z, x0.w, x1.x, x1.y, x1.z, x1.w};

        float inv = __int_as_float(
            __builtin_amdgcn_readlane(__float_as_int(inv_own), tt));

        float e[3];
#pragma unroll
        for (int j = 0; j < 3; ++j) {
            float acc = -csq2[j];
#pragma unroll
            for (int c = 0; c < C_; ++c) acc = fmaf(cen[j][c], xv[c], acc);
            e[j] = EXP2F(acc);
        }

        float a0 = e[0] * inv, a1 = e[1] * inv, a2 = e[2] * inv;

        // Coalesced stores: 64 contiguous floats per instruction.
        aout[lane]      = a0;
        aout[lane + 64] = a1;
        if (lane < K_ - 128) aout[lane + 128] = a2;
        aout += K_;

        den[0] += a0; den[1] += a1; den[2] += a2;
#pragma unroll
        for (int c = 0; c < C_; ++c) {
            num[0][c] = fmaf(a0, xv[c], num[0][c]);
            num[1][c] = fmaf(a1, xv[c], num[1][c]);
            num[2][c] = fmaf(a2, xv[c], num[2][c]);
        }
    }

    // ---- cross-wave reduction: serial wave-by-wave RMW into small LDS buffer
    float vals[NACC];
#pragma unroll
    for (int j = 0; j < 3; ++j) {
#pragma unroll
        for (int c = 0; c < C_; ++c) vals[j * C_ + c] = num[j][c];
        vals[24 + j] = den[j];
    }
    for (int w = 0; w < 4; ++w) {
        if (wave == w) {
            if (w == 0) {
#pragma unroll
                for (int i = 0; i < NACC; ++i) red[lane * RSTRIDE + i] = vals[i];
            } else {
#pragma unroll
                for (int i = 0; i < NACC; ++i) red[lane * RSTRIDE + i] += vals[i];
            }
        }
        __syncthreads();
    }

    if (tid < 64) {
#pragma unroll
        for (int j = 0; j < 3; ++j) {
            int k = lane + 64 * j;
            if (k < K_) {
#pragma unroll
                for (int c = 0; c < C_; ++c)
                    atomicAdd(&num_g[((size_t)b * K_ + k) * C_ + c],
                              red[lane * RSTRIDE + j * C_ + c]);
                atomicAdd(&den_g[b * K_ + k], red[lane * RSTRIDE + 24 + j]);
            }
        }
    }
}

// patch[i] = num[i] / (den[i/C] + 1e-8), in place on the num accumulator.
__global__ void finalize_patch(float* __restrict__ patch, const float* __restrict__ den_g) {
    int i = blockIdx.x * blockDim.x + threadIdx.x;
    if (i < B_ * K_ * C_) patch[i] = patch[i] / (den_g[i / C_] + 1e-8f);
}

extern "C" void kernel_launch(void* const* d_in, const int* in_sizes, int n_in,
                              void* d_out, int out_size, void* d_ws, size_t ws_size,
                              hipStream_t stream) {
    const float* x    = (const float*)d_in[0];   // [B,T,C]
    const float* cent = (const float*)d_in[1];   // [K,C]

    float* out        = (float*)d_out;
    float* patch      = out;                           // [B,K,C] = 76800 floats
    float* assign_out = out + (size_t)B_ * K_ * C_;    // [B,T,K]
    float* den_g      = (float*)d_ws;                  // [B,K] = 9600 floats

    // 1) zero accumulators (d_out/d_ws are poisoned 0xAA before every call)
    int nz = B_ * K_ * C_ + B_ * K_;
    zero_accum<<<(nz + TPB - 1) / TPB, TPB, 0, stream>>>(patch, den_g);

    // 2) fused distances -> softmax -> assignment write + num/den accumulation
    int grid = B_ * (T_ / TCHUNK);   // 64 * 16 = 1024 blocks
    softkmeans_main<<<grid, TPB, 0, stream>>>(x, cent, assign_out, patch, den_g);

    // 3) patch = num / (den + 1e-8)
    int np = B_ * K_ * C_;
    finalize_patch<<<(np + TPB - 1) / TPB, TPB, 0, stream>>>(patch, den_g);
}